// Round 12
// baseline (148.894 us; speedup 1.0000x reference)
//
#include <hip/hip_runtime.h>
#include <math.h>

#define BATCH 32
#define TLEN 8192
#define NCH 64           // chunks
#define CLEN 128         // steps per chunk
#define SUBL 8           // steps per sub-chunk
#define NSUB 16          // sub-chunks per chunk
#define NROWS (BATCH*TLEN)   // 262144 rows

typedef _Float16 h2 __attribute__((ext_vector_type(2)));
union HU { unsigned int u; h2 h; };
__device__ __forceinline__ h2 u2h(unsigned int x) { HU t; t.u = x; return t.h; }
__device__ __forceinline__ unsigned int pkh(float a, float b) {
    HU t; t.h = h2{(_Float16)a, (_Float16)b}; return t.u;
}

#if __has_builtin(__builtin_amdgcn_fdot2)
__device__ __forceinline__ float dot2f(h2 a, h2 b, float c) {
    return __builtin_amdgcn_fdot2(a, b, c, false);
}
#else
__device__ __forceinline__ float dot2f(h2 a, h2 b, float c) {
    return fmaf((float)a.x, (float)b.x, fmaf((float)a.y, (float)b.y, c));
}
#endif

// ---------------------------------------------------------------------------
// HiPPO step, tree-form prefix: s <- (I - A/t) s + (x/t) * r
// ---------------------------------------------------------------------------
__device__ __forceinline__ void hippo_step(float s[8], float inv_t, float xb) {
    const float R[8] = {1.0f, 1.7320508075688772f, 2.23606797749979f,
                        2.6457513110645907f, 3.0f, 3.3166247903554f,
                        3.605551275463989f, 3.872983346207417f};
    float q0 = R[0]*s[0], q1 = R[1]*s[1], q2 = R[2]*s[2], q3 = R[3]*s[3];
    float q4 = R[4]*s[4], q5 = R[5]*s[5], q6 = R[6]*s[6];
    float t01 = q0+q1, t23 = q2+q3, t45 = q4+q5;
    float p1 = q0, p2 = t01, p3 = t01+q2, p4 = t01+t23;
    float p5 = p4+q4, p6 = p4+t45, p7 = p6+q6;
    float p[8] = {0.0f, p1, p2, p3, p4, p5, p6, p7};
    #pragma unroll
    for (int n = 0; n < 8; n++) {
        float as = fmaf(R[n], p[n], (float)(n + 1) * s[n]);
        s[n] = fmaf(-inv_t, as, fmaf(xb, R[n], s[n]));
    }
}

// ---------------------------------------------------------------------------
// Kernel A: per-chunk runs with 8-wide batched + double-buffered x loads.
// ---------------------------------------------------------------------------
__global__ void hippo_chunk_kernel(const float* __restrict__ x_seq,
                                   float* __restrict__ Psub,  // [NCH][NSUB][8][8]
                                   float* __restrict__ Vsub,  // [NCH][NSUB][64][8]
                                   float* __restrict__ Pfin,  // [NCH][8][8]
                                   float* __restrict__ Vfin)  // [NCH][64][8]
{
    int chunk = blockIdx.x;
    int tid = threadIdx.x;
    if (tid >= 72) return;
    bool isP = tid >= 64;
    int col = tid - 64;
    int b = tid >> 1, c = tid & 1;

    float s[8];
    #pragma unroll
    for (int n = 0; n < 8; n++) s[n] = (isP && n == col) ? 1.0f : 0.0f;

    int t0c = chunk * CLEN;
    size_t xbase = ((size_t)b * TLEN + t0c) * 2 + c;

    float xl[8];
    #pragma unroll
    for (int k = 0; k < 8; k++)
        xl[k] = isP ? 0.0f : x_seq[xbase + 2 * k];

    #pragma unroll 1
    for (int ii = 0; ii < CLEN; ii += 8) {
        int sub = ii >> 3;
        if (isP) {
            #pragma unroll
            for (int n = 0; n < 8; n++)
                Psub[(((size_t)chunk * NSUB + sub) * 8 + n) * 8 + col] = s[n];
        } else {
            #pragma unroll
            for (int n = 0; n < 8; n++)
                Vsub[(((size_t)chunk * NSUB + sub) * 64 + tid) * 8 + n] = s[n];
        }
        float xn8[8];
        bool more = (ii + 8 < CLEN) && !isP;
        #pragma unroll
        for (int k = 0; k < 8; k++)
            xn8[k] = more ? x_seq[xbase + 2 * (ii + 8 + k)] : 0.0f;

        #pragma unroll
        for (int k = 0; k < 8; k++) {
            float tf = (float)(t0c + ii + k + 1);
            float inv_t = 1.0f / tf;
            hippo_step(s, inv_t, xl[k] * inv_t);
        }
        #pragma unroll
        for (int k = 0; k < 8; k++) xl[k] = xn8[k];
    }
    if (isP) {
        #pragma unroll
        for (int n = 0; n < 8; n++) Pfin[((size_t)chunk * 8 + n) * 8 + col] = s[n];
    } else {
        #pragma unroll
        for (int n = 0; n < 8; n++) Vfin[((size_t)chunk * 64 + tid) * 8 + n] = s[n];
    }
}

// ---------------------------------------------------------------------------
// Kernel B: parallel compose over (seq,n) = 512 threads, LDS state.
// ---------------------------------------------------------------------------
__global__ __launch_bounds__(512) void hippo_compose_kernel(
    const float* __restrict__ Pfin,
    const float* __restrict__ Vfin,
    float* __restrict__ S0)              // [NCH][64][8]
{
    __shared__ float sst[64][8];
    __shared__ float Pl[64];
    int tid = threadIdx.x;
    int seq = tid >> 3, n = tid & 7;

    sst[seq][n] = 0.0f;
    __syncthreads();

    #pragma unroll 1
    for (int ck = 0; ck < NCH; ck++) {
        S0[((size_t)ck * 64 + seq) * 8 + n] = sst[seq][n];
        float acc = Vfin[((size_t)ck * 64 + seq) * 8 + n];
        if (tid < 64) Pl[tid] = Pfin[ck * 64 + tid];
        __syncthreads();
        #pragma unroll
        for (int m = 0; m < 8; m++)
            acc = fmaf(Pl[n * 8 + m], sst[seq][m], acc);
        __syncthreads();
        sst[seq][n] = acc;
    }
}

// ---------------------------------------------------------------------------
// Kernel C: fine expand (reads precomputed S0), f16-pair planes hTu[8][NROWS].
// ---------------------------------------------------------------------------
__global__ __launch_bounds__(256) void hippo_expand_kernel(
    const float* __restrict__ x_seq,
    const float* __restrict__ Psub,
    const float* __restrict__ Vsub,
    const float* __restrict__ S0,
    unsigned int* __restrict__ hTu)      // [8][NROWS] f16-pairs
{
    int tid = threadIdx.x;
    int sub = tid & 15;
    int c = (tid >> 4) & 1;
    int blo = tid >> 5;                  // 0..7
    int bhi = blockIdx.x & 3;            // 0..3
    int chunk = blockIdx.x >> 2;         // 0..63
    int b = bhi * 8 + blo;
    int seq = b * 2 + c;

    float s0v[8];
    #pragma unroll
    for (int n = 0; n < 8; n++)
        s0v[n] = S0[((size_t)chunk * 64 + seq) * 8 + n];

    const float* Pp = &Psub[((size_t)chunk * NSUB + sub) * 64];
    const float* Vp = &Vsub[(((size_t)chunk * NSUB + sub) * 64 + seq) * 8];

    float s[8];
    #pragma unroll
    for (int n = 0; n < 8; n++) {
        float acc = Vp[n];
        #pragma unroll
        for (int m = 0; m < 8; m++)
            acc = fmaf(Pp[n * 8 + m], s0v[m], acc);
        s[n] = acc;
    }

    int t0 = chunk * CLEN + sub * SUBL;
    size_t rowbase = (size_t)b * TLEN;

    unsigned int dw[4][8];
    #pragma unroll
    for (int i = 0; i < SUBL; i++) {
        int t = t0 + i;
        float tf = (float)(t + 1);
        float inv_t = 1.0f / tf;
        float x = x_seq[(rowbase + t) * 2 + c];
        hippo_step(s, inv_t, x * inv_t);
        #pragma unroll
        for (int k = 0; k < 4; k++)
            dw[k][i] = pkh(s[2 * k], s[2 * k + 1]);
    }
    #pragma unroll
    for (int k = 0; k < 4; k++) {
        int plane = c * 4 + k;
        uint4* dst = (uint4*)&hTu[(size_t)plane * NROWS + rowbase + t0];
        dst[0] = make_uint4(dw[k][0], dw[k][1], dw[k][2], dw[k][3]);
        dst[1] = make_uint4(dw[k][4], dw[k][5], dw[k][6], dw[k][7]);
    }
}

// ---------------------------------------------------------------------------
// KAN helpers
// ---------------------------------------------------------------------------
__device__ __forceinline__ void bspline4(float x, float& B0, float& B1,
                                         float& B2, float& B3, int& m)
{
    float tt = fmaf(x, 5.0f, 8.0f);        // (x + 1.6) * 5
    float fm = floorf(tt);
    float u = tt - fm;
    bool valid = (fm >= 0.0f) && (fm <= 15.0f);
    float u2 = u * u, u3 = u2 * u;
    float um = 1.0f - u;
    B0 = um * um * um * (1.0f / 6.0f);
    B3 = u3 * (1.0f / 6.0f);
    B1 = fmaf(3.0f, u3, fmaf(-6.0f, u2, 4.0f)) * (1.0f / 6.0f);
    B2 = fmaf(-3.0f, u3, fmaf(3.0f, u2, fmaf(3.0f, u, 1.0f))) * (1.0f / 6.0f);
    float msk = valid ? 1.0f : 0.0f;
    B0 *= msk; B1 *= msk; B2 *= msk; B3 *= msk;
    m = valid ? (int)fm : 0;
}

__device__ __forceinline__ float silu(float x) {
    return x / (1.0f + __expf(-x));
}

// 512 threads, 64KB slot table (2 blocks/CU, 16 waves/CU) AND a forced
// 128-VGPR budget via __launch_bounds__(512, 4): r11's compiler chose
// VGPR=64, which starved per-wave load pipelining (only ~4 b128 in
// flight). 4 waves/SIMD min -> cap 128 -> both waves AND ILP.
__global__ __launch_bounds__(512, 4) void kan_kernel(
    const unsigned int* __restrict__ hTu,    // [8][NROWS] f16 pairs
    unsigned int* __restrict__ out1Tu,       // [16][NROWS] f16 pairs
    const float* __restrict__ wb1, const float* __restrict__ ws1,
    const float* __restrict__ wb2, const float* __restrict__ ws2,
    const float* __restrict__ wb3, const float* __restrict__ ws3,
    float* __restrict__ out)
{
    __shared__ uint2 wslot[8192];            // 65536 B
    int tid = threadIdx.x;
    int row = blockIdx.x * 512 + tid;

    // ---- stage phase 1: 512 edges (i<16,o<32), 1 per thread
    {
        int i = tid >> 5, o = tid & 31;
        const float* src = ws1 + o * 208 + i * 13;
        unsigned short wp[19];
        #pragma unroll
        for (int j = 0; j < 19; j++) {
            float v = (j >= 3 && j <= 15) ? src[j - 3] : 0.0f;
            HU t; t.h = h2{(_Float16)v, (_Float16)0.0f};
            wp[j] = (unsigned short)(t.u & 0xFFFFu);
        }
        #pragma unroll
        for (int m = 0; m < 16; m++) {
            unsigned int d0 = (unsigned int)wp[m]     | ((unsigned int)wp[m + 1] << 16);
            unsigned int d1 = (unsigned int)wp[m + 2] | ((unsigned int)wp[m + 3] << 16);
            int p = (o + 2 * m) & 31;
            wslot[(i * 16 + m) * 32 + p] = make_uint2(d0, d1);
        }
    }
    __syncthreads();

    // ---- layer 1: 16 -> 32 (rolled over 8 input pairs)
    float acc1[32];
    #pragma unroll
    for (int o = 0; o < 32; o++) acc1[o] = 0.0f;

    unsigned int cur = hTu[row];
    unsigned int nxt = hTu[(size_t)NROWS + row];
    #pragma unroll 1
    for (int pi = 0; pi < 8; pi++) {
        unsigned int fut = hTu[(size_t)((pi + 2) & 7) * NROWS + row];
        h2 xp = u2h(cur);
        #pragma unroll
        for (int par = 0; par < 2; par++) {
            int i = 2 * pi + par;
            float xv = (par == 0) ? (float)xp.x : (float)xp.y;
            float sx = silu(xv);
            float B0, B1, B2, B3; int m;
            bspline4(xv, B0, B1, B2, B3, m);
            h2 B01 = u2h(pkh(B0, B1));
            h2 B23 = u2h(pkh(B2, B3));
            const char* rowp = (const char*)wslot + (i * 4096 + m * 256);
            const float* wbrow = wb1 + i;       // wb1[o*16+i], lane-uniform
            #pragma unroll
            for (int k = 0; k < 16; k++) {
                uint4 d = *(const uint4*)(rowp + (((k + m) & 15) << 4));
                float aE = acc1[2 * k];
                aE = dot2f(B01, u2h(d.x), aE);
                aE = dot2f(B23, u2h(d.y), aE);
                aE = fmaf(sx, wbrow[(2 * k) * 16], aE);
                acc1[2 * k] = aE;
                float aO = acc1[2 * k + 1];
                aO = dot2f(B01, u2h(d.z), aO);
                aO = dot2f(B23, u2h(d.w), aO);
                aO = fmaf(sx, wbrow[(2 * k + 1) * 16], aO);
                acc1[2 * k + 1] = aO;
            }
        }
        cur = nxt; nxt = fut;
    }
    #pragma unroll
    for (int op = 0; op < 16; op++)
        out1Tu[(size_t)op * NROWS + row] = pkh(acc1[2 * op], acc1[2 * op + 1]);

    __syncthreads();   // all waves done reading phase-1 table

    // ---- stage phase 2: 512 edges (i<32,o<16), 1 per thread
    {
        int i = tid >> 4, o = tid & 15;
        const float* src = ws2 + o * 416 + i * 13;
        unsigned short wp[19];
        #pragma unroll
        for (int j = 0; j < 19; j++) {
            float v = (j >= 3 && j <= 15) ? src[j - 3] : 0.0f;
            HU t; t.h = h2{(_Float16)v, (_Float16)0.0f};
            wp[j] = (unsigned short)(t.u & 0xFFFFu);
        }
        #pragma unroll
        for (int m = 0; m < 16; m++) {
            unsigned int d0 = (unsigned int)wp[m]     | ((unsigned int)wp[m + 1] << 16);
            unsigned int d1 = (unsigned int)wp[m + 2] | ((unsigned int)wp[m + 3] << 16);
            int p = (o + 2 * m) & 15;
            wslot[(i * 16 + m) * 16 + p] = make_uint2(d0, d1);
        }
    }
    __syncthreads();

    // ---- layer 2: 32 -> 16 (rolled over 16 input pairs)
    float acc2[16];
    #pragma unroll
    for (int o = 0; o < 16; o++) acc2[o] = 0.0f;

    cur = out1Tu[row];
    nxt = out1Tu[(size_t)NROWS + row];
    #pragma unroll 1
    for (int pi = 0; pi < 16; pi++) {
        unsigned int fut = out1Tu[(size_t)((pi + 2) & 15) * NROWS + row];
        h2 yp = u2h(cur);
        #pragma unroll
        for (int par = 0; par < 2; par++) {
            int i = 2 * pi + par;
            float yv = (par == 0) ? (float)yp.x : (float)yp.y;
            float sx = silu(yv);
            float B0, B1, B2, B3; int m;
            bspline4(yv, B0, B1, B2, B3, m);
            h2 B01 = u2h(pkh(B0, B1));
            h2 B23 = u2h(pkh(B2, B3));
            const char* rowp = (const char*)wslot + (i * 2048 + m * 128);
            const float* wbrow = wb2 + i;       // wb2[o*32+i], lane-uniform
            #pragma unroll
            for (int k = 0; k < 8; k++) {
                uint4 d = *(const uint4*)(rowp + (((k + m) & 7) << 4));
                float aE = acc2[2 * k];
                aE = dot2f(B01, u2h(d.x), aE);
                aE = dot2f(B23, u2h(d.y), aE);
                aE = fmaf(sx, wbrow[(2 * k) * 32], aE);
                acc2[2 * k] = aE;
                float aO = acc2[2 * k + 1];
                aO = dot2f(B01, u2h(d.z), aO);
                aO = dot2f(B23, u2h(d.w), aO);
                aO = fmaf(sx, wbrow[(2 * k + 1) * 32], aO);
                acc2[2 * k + 1] = aO;
            }
        }
        cur = nxt; nxt = fut;
    }

    // ---- layer 3: 16 -> 1, fully unrolled, fp32 weights from global
    float acc3 = 0.0f;
    #pragma unroll
    for (int i = 0; i < 16; i++) {
        float xv = acc2[i];
        float sx = silu(xv);
        float B0, B1, B2, B3; int m;
        bspline4(xv, B0, B1, B2, B3, m);
        acc3 = fmaf(sx, wb3[i], acc3);
        const float* w3 = &ws3[i * 13];
        int j0 = m - 3;
        float w0v = (j0 >= 0)              ? w3[j0]     : 0.0f;
        float w1v = (j0 >= -1 && j0 <= 11) ? w3[j0 + 1] : 0.0f;
        float w2v = (j0 >= -2 && j0 <= 10) ? w3[j0 + 2] : 0.0f;
        float w3v = (j0 <= 9)              ? w3[j0 + 3] : 0.0f;
        acc3 = fmaf(B0, w0v, acc3);
        acc3 = fmaf(B1, w1v, acc3);
        acc3 = fmaf(B2, w2v, acc3);
        acc3 = fmaf(B3, w3v, acc3);
    }
    out[row] = acc3;
}

// ---------------------------------------------------------------------------
extern "C" void kernel_launch(void* const* d_in, const int* in_sizes, int n_in,
                              void* d_out, int out_size, void* d_ws, size_t ws_size,
                              hipStream_t stream) {
    const float* x_seq = (const float*)d_in[0];
    const float* wb1   = (const float*)d_in[1];
    const float* ws1   = (const float*)d_in[2];
    const float* wb2   = (const float*)d_in[3];
    const float* ws2   = (const float*)d_in[4];
    const float* wb3   = (const float*)d_in[5];
    const float* ws3   = (const float*)d_in[6];

    float* ws   = (float*)d_ws;
    float* Psub = ws;                   // 64*16*64        =   65536
    float* Vsub = ws + 65536;           // 64*16*64*8      =  524288
    float* Pfin = ws + 589824;          // 64*64           =    4096
    float* Vfin = ws + 593920;          // 64*64*8         =   32768
    float* S0   = ws + 626688;          // 64*64*8         =   32768
    unsigned int* hTu    = (unsigned int*)(ws + 659456);   // 8*262144  dw
    unsigned int* out1Tu = (unsigned int*)(ws + 2756608);  // 16*262144 dw
    float* out  = (float*)d_out;

    hipLaunchKernelGGL(hippo_chunk_kernel,   dim3(NCH), dim3(128), 0, stream,
                       x_seq, Psub, Vsub, Pfin, Vfin);
    hipLaunchKernelGGL(hippo_compose_kernel, dim3(1),   dim3(512), 0, stream,
                       Pfin, Vfin, S0);
    hipLaunchKernelGGL(hippo_expand_kernel,  dim3(NCH * 4), dim3(256), 0, stream,
                       x_seq, Psub, Vsub, S0, hTu);
    hipLaunchKernelGGL(kan_kernel, dim3(NROWS / 512), dim3(512), 0, stream,
                       hTu, out1Tu, wb1, ws1, wb2, ws2, wb3, ws3, out);
}

// Round 13
// 130.194 us; speedup vs baseline: 1.1436x; 1.1436x over previous
//
#include <hip/hip_runtime.h>
#include <math.h>

#define BATCH 32
#define TLEN 8192
#define NCH 128          // chunks
#define CLEN 64          // steps per chunk
#define SUBL 8           // steps per sub-chunk
#define NSUB 8           // sub-chunks per chunk
#define NROWS (BATCH*TLEN)   // 262144 rows

typedef _Float16 h2 __attribute__((ext_vector_type(2)));
union HU { unsigned int u; h2 h; };
__device__ __forceinline__ h2 u2h(unsigned int x) { HU t; t.u = x; return t.h; }
__device__ __forceinline__ unsigned int pkh(float a, float b) {
    HU t; t.h = h2{(_Float16)a, (_Float16)b}; return t.u;
}

#if __has_builtin(__builtin_amdgcn_fdot2)
__device__ __forceinline__ float dot2f(h2 a, h2 b, float c) {
    return __builtin_amdgcn_fdot2(a, b, c, false);
}
#else
__device__ __forceinline__ float dot2f(h2 a, h2 b, float c) {
    return fmaf((float)a.x, (float)b.x, fmaf((float)a.y, (float)b.y, c));
}
#endif

// ---------------------------------------------------------------------------
// HiPPO step, tree-form prefix: s <- (I - A/t) s + (x/t) * r
// ---------------------------------------------------------------------------
__device__ __forceinline__ void hippo_step(float s[8], float inv_t, float xb) {
    const float R[8] = {1.0f, 1.7320508075688772f, 2.23606797749979f,
                        2.6457513110645907f, 3.0f, 3.3166247903554f,
                        3.605551275463989f, 3.872983346207417f};
    float q0 = R[0]*s[0], q1 = R[1]*s[1], q2 = R[2]*s[2], q3 = R[3]*s[3];
    float q4 = R[4]*s[4], q5 = R[5]*s[5], q6 = R[6]*s[6];
    float t01 = q0+q1, t23 = q2+q3, t45 = q4+q5;
    float p1 = q0, p2 = t01, p3 = t01+q2, p4 = t01+t23;
    float p5 = p4+q4, p6 = p4+t45, p7 = p6+q6;
    float p[8] = {0.0f, p1, p2, p3, p4, p5, p6, p7};
    #pragma unroll
    for (int n = 0; n < 8; n++) {
        float as = fmaf(R[n], p[n], (float)(n + 1) * s[n]);
        s[n] = fmaf(-inv_t, as, fmaf(xb, R[n], s[n]));
    }
}

// ---------------------------------------------------------------------------
// Kernel A: per-chunk runs (CLEN=64) with 8-wide batched + prefetched x loads.
// ---------------------------------------------------------------------------
__global__ void hippo_chunk_kernel(const float* __restrict__ x_seq,
                                   float* __restrict__ Psub,  // [NCH][NSUB][8][8]
                                   float* __restrict__ Vsub,  // [NCH][NSUB][64][8]
                                   float* __restrict__ Pfin,  // [NCH][8][8]
                                   float* __restrict__ Vfin)  // [NCH][64][8]
{
    int chunk = blockIdx.x;
    int tid = threadIdx.x;
    if (tid >= 72) return;
    bool isP = tid >= 64;
    int col = tid - 64;
    int b = tid >> 1, c = tid & 1;

    float s[8];
    #pragma unroll
    for (int n = 0; n < 8; n++) s[n] = (isP && n == col) ? 1.0f : 0.0f;

    int t0c = chunk * CLEN;
    size_t xbase = ((size_t)b * TLEN + t0c) * 2 + c;

    float xl[8];
    #pragma unroll
    for (int k = 0; k < 8; k++)
        xl[k] = isP ? 0.0f : x_seq[xbase + 2 * k];

    #pragma unroll 1
    for (int ii = 0; ii < CLEN; ii += 8) {
        int sub = ii >> 3;
        if (isP) {
            #pragma unroll
            for (int n = 0; n < 8; n++)
                Psub[(((size_t)chunk * NSUB + sub) * 8 + n) * 8 + col] = s[n];
        } else {
            #pragma unroll
            for (int n = 0; n < 8; n++)
                Vsub[(((size_t)chunk * NSUB + sub) * 64 + tid) * 8 + n] = s[n];
        }
        float xn8[8];
        bool more = (ii + 8 < CLEN) && !isP;
        #pragma unroll
        for (int k = 0; k < 8; k++)
            xn8[k] = more ? x_seq[xbase + 2 * (ii + 8 + k)] : 0.0f;

        #pragma unroll
        for (int k = 0; k < 8; k++) {
            float tf = (float)(t0c + ii + k + 1);
            float inv_t = 1.0f / tf;
            hippo_step(s, inv_t, xl[k] * inv_t);
        }
        #pragma unroll
        for (int k = 0; k < 8; k++) xl[k] = xn8[k];
    }
    if (isP) {
        #pragma unroll
        for (int n = 0; n < 8; n++) Pfin[((size_t)chunk * 8 + n) * 8 + col] = s[n];
    } else {
        #pragma unroll
        for (int n = 0; n < 8; n++) Vfin[((size_t)chunk * 64 + tid) * 8 + n] = s[n];
    }
}

// ---------------------------------------------------------------------------
// Kernel B: barrier-free compose. Each seq's 8 states live in 8 adjacent
// lanes; cross-state reads via __shfl(width 8). P/V register-prefetched.
// ---------------------------------------------------------------------------
__global__ __launch_bounds__(512) void hippo_compose_kernel(
    const float* __restrict__ Pfin,
    const float* __restrict__ Vfin,
    float* __restrict__ S0)              // [NCH][64][8]
{
    int tid = threadIdx.x;               // 512 = 64 seq * 8 n
    int n = tid & 7;

    float cur = 0.0f;
    float vr = Vfin[tid];
    float pr[8];
    #pragma unroll
    for (int m = 0; m < 8; m++) pr[m] = Pfin[n * 8 + m];

    #pragma unroll 1
    for (int ck = 0; ck < NCH; ck++) {
        int nk = (ck + 1 < NCH) ? (ck + 1) : ck;
        float vn = Vfin[(size_t)nk * 512 + tid];
        float pn[8];
        #pragma unroll
        for (int m = 0; m < 8; m++) pn[m] = Pfin[nk * 64 + n * 8 + m];

        S0[(size_t)ck * 512 + tid] = cur;
        float acc = vr;
        #pragma unroll
        for (int m = 0; m < 8; m++) {
            float sm = __shfl(cur, m, 8);
            acc = fmaf(pr[m], sm, acc);
        }
        cur = acc;
        vr = vn;
        #pragma unroll
        for (int m = 0; m < 8; m++) pr[m] = pn[m];
    }
}

// ---------------------------------------------------------------------------
// KAN helpers
// ---------------------------------------------------------------------------
__device__ __forceinline__ void bspline4(float x, float& B0, float& B1,
                                         float& B2, float& B3, int& m)
{
    float tt = fmaf(x, 5.0f, 8.0f);        // (x + 1.6) * 5
    float fm = floorf(tt);
    float u = tt - fm;
    bool valid = (fm >= 0.0f) && (fm <= 15.0f);
    float u2 = u * u, u3 = u2 * u;
    float um = 1.0f - u;
    B0 = um * um * um * (1.0f / 6.0f);
    B3 = u3 * (1.0f / 6.0f);
    B1 = fmaf(3.0f, u3, fmaf(-6.0f, u2, 4.0f)) * (1.0f / 6.0f);
    B2 = fmaf(-3.0f, u3, fmaf(3.0f, u2, fmaf(3.0f, u, 1.0f))) * (1.0f / 6.0f);
    float msk = valid ? 1.0f : 0.0f;
    B0 *= msk; B1 *= msk; B2 *= msk; B3 *= msk;
    m = valid ? (int)fm : 0;
}

__device__ __forceinline__ float silu(float x) {
    return x / (1.0f + __expf(-x));
}

// FUSED EXPAND + KAN (r8 core): threads 0..63 replay this block's 32
// sub-chunks x 2 channels into LDS hbuf (f16 pairs, row stride 17 dwords =
// conflict-free: 17 coprime 32) while all threads stage phase-1 weights.
// Layer-1 output also round-trips through hbuf (own row only -> no barrier).
// Kills the expand kernel + the hTu & out1T global round-trips.
__global__ __launch_bounds__(256) void kan_kernel(
    const float* __restrict__ x_seq,
    const float* __restrict__ Psub,
    const float* __restrict__ Vsub,
    const float* __restrict__ S0,
    const float* __restrict__ wb1, const float* __restrict__ ws1,
    const float* __restrict__ wb2, const float* __restrict__ ws2,
    const float* __restrict__ wb3, const float* __restrict__ ws3,
    float* __restrict__ out)
{
    __shared__ unsigned int wldsU[9728];       // 38912 B weights
    __shared__ unsigned int hbuf[256 * 17];    // 17408 B activations
    int tid = threadIdx.x;
    int b = blockIdx.x >> 5;                   // 0..31
    int tseg = blockIdx.x & 31;                // 0..31
    int row = blockIdx.x * 256 + tid;          // = b*TLEN + tseg*256 + tid

    // ---- fused expand: 32 sub-chunks x 2 c -> hbuf rows 0..255
    if (tid < 64) {
        int uc = tid >> 1;                     // 0..31
        int c = tid & 1;
        int chunk = (tseg << 2) + (uc >> 3);   // 4 chunks per block
        int sub = uc & 7;
        int seq = b * 2 + c;
        int row_loc = uc << 3;                 // chunk_loc*64 + sub*8 = 8*uc

        float s0v[8];
        #pragma unroll
        for (int n = 0; n < 8; n++)
            s0v[n] = S0[((size_t)chunk * 64 + seq) * 8 + n];

        const float* Pp = &Psub[((size_t)chunk * NSUB + sub) * 64];
        const float* Vp = &Vsub[(((size_t)chunk * NSUB + sub) * 64 + seq) * 8];

        float s[8];
        #pragma unroll
        for (int n = 0; n < 8; n++) {
            float acc = Vp[n];
            #pragma unroll
            for (int m = 0; m < 8; m++)
                acc = fmaf(Pp[n * 8 + m], s0v[m], acc);
            s[n] = acc;
        }

        int t0 = chunk * CLEN + sub * SUBL;
        float xv8[8];
        #pragma unroll
        for (int k = 0; k < 8; k++)
            xv8[k] = x_seq[((size_t)b * TLEN + t0 + k) * 2 + c];

        #pragma unroll
        for (int i = 0; i < SUBL; i++) {
            float tf = (float)(t0 + i + 1);
            float inv_t = 1.0f / tf;
            hippo_step(s, inv_t, xv8[i] * inv_t);
            #pragma unroll
            for (int k = 0; k < 4; k++)
                hbuf[(row_loc + i) * 17 + c * 4 + k] = pkh(s[2 * k], s[2 * k + 1]);
        }
    }

    // ---- stage phase 1 (affine, all threads; overlaps expand latency)
    {
        int i = tid >> 4, q = tid & 15;
        #pragma unroll
        for (int oo = 0; oo < 2; oo++) {
            int o = q + oo * 16;
            const float* src = ws1 + o * 208 + i * 13;
            int dst = i * 608 + o * 19;
            #pragma unroll
            for (int p = 0; p < 19; p++) {
                int j0 = (p < 10) ? (2 * p) : (2 * (p - 10) + 1);
                float lo = (j0 >= 3 && j0 <= 15) ? src[j0 - 3] : 0.0f;
                float hi = (j0 + 1 >= 3 && j0 + 1 <= 15) ? src[j0 - 2] : 0.0f;
                wldsU[dst + p] = pkh(lo, hi);
            }
        }
    }
    __syncthreads();

    // ---- layer 1: 16 -> 32 (rolled over 8 input pairs from hbuf)
    float acc1[32];
    #pragma unroll
    for (int o = 0; o < 32; o++) acc1[o] = 0.0f;

    #pragma unroll 1
    for (int pi = 0; pi < 8; pi++) {
        h2 xp = u2h(hbuf[tid * 17 + pi]);
        #pragma unroll
        for (int par = 0; par < 2; par++) {
            int i = 2 * pi + par;
            float xv = (par == 0) ? (float)xp.x : (float)xp.y;
            float sx = silu(xv);
            float B0, B1, B2, B3; int m;
            bspline4(xv, B0, B1, B2, B3, m);
            h2 B01 = u2h(pkh(B0, B1));
            h2 B23 = u2h(pkh(B2, B3));
            int poff = (m & 1) ? (10 + ((m - 1) >> 1)) : (m >> 1);
            int base = i * 608 + poff;
            const float* wbrow = wb1 + i;       // wb1[o*16+i]
            #pragma unroll
            for (int o = 0; o < 32; o++) {
                unsigned int da = wldsU[base + o * 19];
                unsigned int db = wldsU[base + o * 19 + 1];
                float a = acc1[o];
                a = dot2f(B01, u2h(da), a);
                a = dot2f(B23, u2h(db), a);
                a = fmaf(sx, wbrow[o * 16], a);
                acc1[o] = a;
            }
        }
    }
    // dump layer-1 output to own hbuf row (no cross-thread hazard)
    #pragma unroll
    for (int op = 0; op < 16; op++)
        hbuf[tid * 17 + op] = pkh(acc1[2 * op], acc1[2 * op + 1]);

    __syncthreads();   // all waves done reading phase-1 weights

    // ---- stage phase 2 (affine)
    {
        int i = tid >> 3, q = tid & 7;
        #pragma unroll
        for (int oo = 0; oo < 2; oo++) {
            int o = q + oo * 8;
            const float* src = ws2 + o * 416 + i * 13;
            int dst = i * 304 + o * 19;
            #pragma unroll
            for (int p = 0; p < 19; p++) {
                int j0 = (p < 10) ? (2 * p) : (2 * (p - 10) + 1);
                float lo = (j0 >= 3 && j0 <= 15) ? src[j0 - 3] : 0.0f;
                float hi = (j0 + 1 >= 3 && j0 + 1 <= 15) ? src[j0 - 2] : 0.0f;
                wldsU[dst + p] = pkh(lo, hi);
            }
        }
    }
    __syncthreads();

    // ---- layer 2: 32 -> 16 (rolled over 16 input pairs from hbuf)
    float acc2[16];
    #pragma unroll
    for (int o = 0; o < 16; o++) acc2[o] = 0.0f;

    #pragma unroll 1
    for (int pi = 0; pi < 16; pi++) {
        h2 yp = u2h(hbuf[tid * 17 + pi]);
        #pragma unroll
        for (int par = 0; par < 2; par++) {
            int i = 2 * pi + par;
            float yv = (par == 0) ? (float)yp.x : (float)yp.y;
            float sx = silu(yv);
            float B0, B1, B2, B3; int m;
            bspline4(yv, B0, B1, B2, B3, m);
            h2 B01 = u2h(pkh(B0, B1));
            h2 B23 = u2h(pkh(B2, B3));
            int poff = (m & 1) ? (10 + ((m - 1) >> 1)) : (m >> 1);
            int base = i * 304 + poff;
            const float* wbrow = wb2 + i;       // wb2[o*32+i]
            #pragma unroll
            for (int o = 0; o < 16; o++) {
                unsigned int da = wldsU[base + o * 19];
                unsigned int db = wldsU[base + o * 19 + 1];
                float a = acc2[o];
                a = dot2f(B01, u2h(da), a);
                a = dot2f(B23, u2h(db), a);
                a = fmaf(sx, wbrow[o * 32], a);
                acc2[o] = a;
            }
        }
    }

    // ---- layer 3: 16 -> 1, fully unrolled, fp32 weights from global
    float acc3 = 0.0f;
    #pragma unroll
    for (int i = 0; i < 16; i++) {
        float xv = acc2[i];
        float sx = silu(xv);
        float B0, B1, B2, B3; int m;
        bspline4(xv, B0, B1, B2, B3, m);
        acc3 = fmaf(sx, wb3[i], acc3);
        const float* w3 = &ws3[i * 13];
        int j0 = m - 3;
        float w0v = (j0 >= 0)              ? w3[j0]     : 0.0f;
        float w1v = (j0 >= -1 && j0 <= 11) ? w3[j0 + 1] : 0.0f;
        float w2v = (j0 >= -2 && j0 <= 10) ? w3[j0 + 2] : 0.0f;
        float w3v = (j0 <= 9)              ? w3[j0 + 3] : 0.0f;
        acc3 = fmaf(B0, w0v, acc3);
        acc3 = fmaf(B1, w1v, acc3);
        acc3 = fmaf(B2, w2v, acc3);
        acc3 = fmaf(B3, w3v, acc3);
    }
    out[row] = acc3;
}

// ---------------------------------------------------------------------------
extern "C" void kernel_launch(void* const* d_in, const int* in_sizes, int n_in,
                              void* d_out, int out_size, void* d_ws, size_t ws_size,
                              hipStream_t stream) {
    const float* x_seq = (const float*)d_in[0];
    const float* wb1   = (const float*)d_in[1];
    const float* ws1   = (const float*)d_in[2];
    const float* wb2   = (const float*)d_in[3];
    const float* ws2   = (const float*)d_in[4];
    const float* wb3   = (const float*)d_in[5];
    const float* ws3   = (const float*)d_in[6];

    float* ws   = (float*)d_ws;
    float* Psub = ws;                   // 128*8*64        =   65536
    float* Vsub = ws + 65536;           // 128*8*64*8      =  524288
    float* Pfin = ws + 589824;          // 128*64          =    8192
    float* Vfin = ws + 598016;          // 128*64*8        =   65536
    float* S0   = ws + 663552;          // 128*64*8        =   65536
    float* out  = (float*)d_out;

    hipLaunchKernelGGL(hippo_chunk_kernel,   dim3(NCH), dim3(128), 0, stream,
                       x_seq, Psub, Vsub, Pfin, Vfin);
    hipLaunchKernelGGL(hippo_compose_kernel, dim3(1),   dim3(512), 0, stream,
                       Pfin, Vfin, S0);
    hipLaunchKernelGGL(kan_kernel, dim3(NROWS / 256), dim3(256), 0, stream,
                       x_seq, Psub, Vsub, S0,
                       wb1, ws1, wb2, ws2, wb3, ws3, out);
}

// Round 15
// 123.391 us; speedup vs baseline: 1.2067x; 1.0551x over previous
//
#include <hip/hip_runtime.h>
#include <math.h>

#define BATCH 32
#define TLEN 8192
#define NCH 128          // chunks
#define CLEN 64          // steps per chunk
#define SUBL 8           // steps per sub-chunk
#define NSUB 8           // sub-chunks per chunk
#define NROWS (BATCH*TLEN)   // 262144 rows

typedef _Float16 h2 __attribute__((ext_vector_type(2)));
union HU { unsigned int u; h2 h; };
__device__ __forceinline__ h2 u2h(unsigned int x) { HU t; t.u = x; return t.h; }
__device__ __forceinline__ unsigned int pkh(float a, float b) {
    HU t; t.h = h2{(_Float16)a, (_Float16)b}; return t.u;
}

#if __has_builtin(__builtin_amdgcn_fdot2)
__device__ __forceinline__ float dot2f(h2 a, h2 b, float c) {
    return __builtin_amdgcn_fdot2(a, b, c, false);
}
#else
__device__ __forceinline__ float dot2f(h2 a, h2 b, float c) {
    return fmaf((float)a.x, (float)b.x, fmaf((float)a.y, (float)b.y, c));
}
#endif

// ---------------------------------------------------------------------------
// HiPPO step, tree-form prefix: s <- (I - A/t) s + (x/t) * r
// ---------------------------------------------------------------------------
__device__ __forceinline__ void hippo_step(float s[8], float inv_t, float xb) {
    const float R[8] = {1.0f, 1.7320508075688772f, 2.23606797749979f,
                        2.6457513110645907f, 3.0f, 3.3166247903554f,
                        3.605551275463989f, 3.872983346207417f};
    float q0 = R[0]*s[0], q1 = R[1]*s[1], q2 = R[2]*s[2], q3 = R[3]*s[3];
    float q4 = R[4]*s[4], q5 = R[5]*s[5], q6 = R[6]*s[6];
    float t01 = q0+q1, t23 = q2+q3, t45 = q4+q5;
    float p1 = q0, p2 = t01, p3 = t01+q2, p4 = t01+t23;
    float p5 = p4+q4, p6 = p4+t45, p7 = p6+q6;
    float p[8] = {0.0f, p1, p2, p3, p4, p5, p6, p7};
    #pragma unroll
    for (int n = 0; n < 8; n++) {
        float as = fmaf(R[n], p[n], (float)(n + 1) * s[n]);
        s[n] = fmaf(-inv_t, as, fmaf(xb, R[n], s[n]));
    }
}

// ---------------------------------------------------------------------------
// Kernel A: per-chunk runs (CLEN=64) with 8-wide batched + prefetched x loads.
// ---------------------------------------------------------------------------
__global__ void hippo_chunk_kernel(const float* __restrict__ x_seq,
                                   float* __restrict__ Psub,  // [NCH][NSUB][8][8]
                                   float* __restrict__ Vsub,  // [NCH][NSUB][64][8]
                                   float* __restrict__ Pfin,  // [NCH][8][8]
                                   float* __restrict__ Vfin)  // [NCH][64][8]
{
    int chunk = blockIdx.x;
    int tid = threadIdx.x;
    if (tid >= 72) return;
    bool isP = tid >= 64;
    int col = tid - 64;
    int b = tid >> 1, c = tid & 1;

    float s[8];
    #pragma unroll
    for (int n = 0; n < 8; n++) s[n] = (isP && n == col) ? 1.0f : 0.0f;

    int t0c = chunk * CLEN;
    size_t xbase = ((size_t)b * TLEN + t0c) * 2 + c;

    float xl[8];
    #pragma unroll
    for (int k = 0; k < 8; k++)
        xl[k] = isP ? 0.0f : x_seq[xbase + 2 * k];

    #pragma unroll 1
    for (int ii = 0; ii < CLEN; ii += 8) {
        int sub = ii >> 3;
        if (isP) {
            #pragma unroll
            for (int n = 0; n < 8; n++)
                Psub[(((size_t)chunk * NSUB + sub) * 8 + n) * 8 + col] = s[n];
        } else {
            #pragma unroll
            for (int n = 0; n < 8; n++)
                Vsub[(((size_t)chunk * NSUB + sub) * 64 + tid) * 8 + n] = s[n];
        }
        float xn8[8];
        bool more = (ii + 8 < CLEN) && !isP;
        #pragma unroll
        for (int k = 0; k < 8; k++)
            xn8[k] = more ? x_seq[xbase + 2 * (ii + 8 + k)] : 0.0f;

        #pragma unroll
        for (int k = 0; k < 8; k++) {
            float tf = (float)(t0c + ii + k + 1);
            float inv_t = 1.0f / tf;
            hippo_step(s, inv_t, xl[k] * inv_t);
        }
        #pragma unroll
        for (int k = 0; k < 8; k++) xl[k] = xn8[k];
    }
    if (isP) {
        #pragma unroll
        for (int n = 0; n < 8; n++) Pfin[((size_t)chunk * 8 + n) * 8 + col] = s[n];
    } else {
        #pragma unroll
        for (int n = 0; n < 8; n++) Vfin[((size_t)chunk * 64 + tid) * 8 + n] = s[n];
    }
}

// ---------------------------------------------------------------------------
// Kernel B: barrier-free compose (shfl width 8, register-prefetched P/V).
// ---------------------------------------------------------------------------
__global__ __launch_bounds__(512) void hippo_compose_kernel(
    const float* __restrict__ Pfin,
    const float* __restrict__ Vfin,
    float* __restrict__ S0)              // [NCH][64][8]
{
    int tid = threadIdx.x;               // 512 = 64 seq * 8 n
    int n = tid & 7;

    float cur = 0.0f;
    float vr = Vfin[tid];
    float pr[8];
    #pragma unroll
    for (int m = 0; m < 8; m++) pr[m] = Pfin[n * 8 + m];

    #pragma unroll 1
    for (int ck = 0; ck < NCH; ck++) {
        int nk = (ck + 1 < NCH) ? (ck + 1) : ck;
        float vn = Vfin[(size_t)nk * 512 + tid];
        float pn[8];
        #pragma unroll
        for (int m = 0; m < 8; m++) pn[m] = Pfin[nk * 64 + n * 8 + m];

        S0[(size_t)ck * 512 + tid] = cur;
        float acc = vr;
        #pragma unroll
        for (int m = 0; m < 8; m++) {
            float sm = __shfl(cur, m, 8);
            acc = fmaf(pr[m], sm, acc);
        }
        cur = acc;
        vr = vn;
        #pragma unroll
        for (int m = 0; m < 8; m++) pr[m] = pn[m];
    }
}

// ---------------------------------------------------------------------------
// KAN helpers
// ---------------------------------------------------------------------------
__device__ __forceinline__ void bspline4(float x, float& B0, float& B1,
                                         float& B2, float& B3, int& m)
{
    float tt = fmaf(x, 5.0f, 8.0f);        // (x + 1.6) * 5
    float fm = floorf(tt);
    float u = tt - fm;
    bool valid = (fm >= 0.0f) && (fm <= 15.0f);
    float u2 = u * u, u3 = u2 * u;
    float um = 1.0f - u;
    B0 = um * um * um * (1.0f / 6.0f);
    B3 = u3 * (1.0f / 6.0f);
    B1 = fmaf(3.0f, u3, fmaf(-6.0f, u2, 4.0f)) * (1.0f / 6.0f);
    B2 = fmaf(-3.0f, u3, fmaf(3.0f, u2, fmaf(3.0f, u, 1.0f))) * (1.0f / 6.0f);
    float msk = valid ? 1.0f : 0.0f;
    B0 *= msk; B1 *= msk; B2 *= msk; B3 *= msk;
    m = valid ? (int)fm : 0;
}

__device__ __forceinline__ float silu(float x) {
    return x / (1.0f + __expf(-x));
}

// FUSED EXPAND + KAN, LDS diet: 38912 B weights + 9216 B hbuf = 48128 B
// -> 3 blocks/CU (12 waves/CU; r10/r13 had 8 waves, VALUBusy ~58%).
// hbuf = 9 dwords/row; slots rotated by (row>>3)&7 so stride-9 rows stay
// conflict-spread. Layer-1->2 handoff in two 8-dword halves: acc1[0..15]
// written before the weight restage, acc1[16..31] carried in registers
// through layer-2 half 0 then written (own-row, no barrier needed).
__global__ __launch_bounds__(256) void kan_kernel(
    const float* __restrict__ x_seq,
    const float* __restrict__ Psub,
    const float* __restrict__ Vsub,
    const float* __restrict__ S0,
    const float* __restrict__ wb1, const float* __restrict__ ws1,
    const float* __restrict__ wb2, const float* __restrict__ ws2,
    const float* __restrict__ wb3, const float* __restrict__ ws3,
    float* __restrict__ out)
{
    __shared__ unsigned int wldsU[9728];     // 38912 B weights
    __shared__ unsigned int hbuf[256 * 9];   //  9216 B activations
    int tid = threadIdx.x;
    int b = blockIdx.x >> 5;                 // 0..31
    int tseg = blockIdx.x & 31;              // 0..31
    int row = blockIdx.x * 256 + tid;
    int rot = (tid >> 3) & 7;

    // ---- fused expand: 32 sub-chunks x 2 c -> hbuf rows (8 of 9 dwords/row)
    if (tid < 64) {
        int uc = tid >> 1;                   // 0..31
        int c = tid & 1;
        int chunk = (tseg << 2) + (uc >> 3); // 4 chunks per block
        int sub = uc & 7;
        int seq = b * 2 + c;
        int row_loc = uc << 3;
        int urot = uc & 7;

        float s0v[8];
        #pragma unroll
        for (int n = 0; n < 8; n++)
            s0v[n] = S0[((size_t)chunk * 64 + seq) * 8 + n];

        const float* Pp = &Psub[((size_t)chunk * NSUB + sub) * 64];
        const float* Vp = &Vsub[(((size_t)chunk * NSUB + sub) * 64 + seq) * 8];

        float s[8];
        #pragma unroll
        for (int n = 0; n < 8; n++) {
            float acc = Vp[n];
            #pragma unroll
            for (int m = 0; m < 8; m++)
                acc = fmaf(Pp[n * 8 + m], s0v[m], acc);
            s[n] = acc;
        }

        int t0 = chunk * CLEN + sub * SUBL;
        float xv8[8];
        #pragma unroll
        for (int k = 0; k < 8; k++)
            xv8[k] = x_seq[((size_t)b * TLEN + t0 + k) * 2 + c];

        #pragma unroll
        for (int i = 0; i < SUBL; i++) {
            float tf = (float)(t0 + i + 1);
            float inv_t = 1.0f / tf;
            hippo_step(s, inv_t, xv8[i] * inv_t);
            #pragma unroll
            for (int k = 0; k < 4; k++)
                hbuf[(row_loc + i) * 9 + ((c * 4 + k + urot) & 7)] =
                    pkh(s[2 * k], s[2 * k + 1]);
        }
    }

    // ---- stage phase 1 (all threads; overlaps expand latency)
    {
        int i = tid >> 4, q = tid & 15;
        #pragma unroll
        for (int oo = 0; oo < 2; oo++) {
            int o = q + oo * 16;
            const float* src = ws1 + o * 208 + i * 13;
            int dst = i * 608 + o * 19;
            #pragma unroll
            for (int p = 0; p < 19; p++) {
                int j0 = (p < 10) ? (2 * p) : (2 * (p - 10) + 1);
                float lo = (j0 >= 3 && j0 <= 15) ? src[j0 - 3] : 0.0f;
                float hi = (j0 + 1 >= 3 && j0 + 1 <= 15) ? src[j0 - 2] : 0.0f;
                wldsU[dst + p] = pkh(lo, hi);
            }
        }
    }
    __syncthreads();

    // ---- layer 1: 16 -> 32 (rolled over 8 input pairs from hbuf)
    float acc1[32];
    #pragma unroll
    for (int o = 0; o < 32; o++) acc1[o] = 0.0f;

    #pragma unroll 1
    for (int pi = 0; pi < 8; pi++) {
        h2 xp = u2h(hbuf[tid * 9 + ((pi + rot) & 7)]);
        #pragma unroll
        for (int par = 0; par < 2; par++) {
            int i = 2 * pi + par;
            float xv = (par == 0) ? (float)xp.x : (float)xp.y;
            float sx = silu(xv);
            float B0, B1, B2, B3; int m;
            bspline4(xv, B0, B1, B2, B3, m);
            h2 B01 = u2h(pkh(B0, B1));
            h2 B23 = u2h(pkh(B2, B3));
            int poff = (m & 1) ? (10 + ((m - 1) >> 1)) : (m >> 1);
            int base = i * 608 + poff;
            const float* wbrow = wb1 + i;       // wb1[o*16+i]
            #pragma unroll
            for (int o = 0; o < 32; o++) {
                unsigned int da = wldsU[base + o * 19];
                unsigned int db = wldsU[base + o * 19 + 1];
                float a = acc1[o];
                a = dot2f(B01, u2h(da), a);
                a = dot2f(B23, u2h(db), a);
                a = fmaf(sx, wbrow[o * 16], a);
                acc1[o] = a;
            }
        }
    }
    // first half of layer-1 output -> own hbuf row
    #pragma unroll
    for (int op = 0; op < 8; op++)
        hbuf[tid * 9 + ((op + rot) & 7)] = pkh(acc1[2 * op], acc1[2 * op + 1]);

    __syncthreads();   // all waves done reading phase-1 weights

    // ---- stage phase 2
    {
        int i = tid >> 3, q = tid & 7;
        #pragma unroll
        for (int oo = 0; oo < 2; oo++) {
            int o = q + oo * 8;
            const float* src = ws2 + o * 416 + i * 13;
            int dst = i * 304 + o * 19;
            #pragma unroll
            for (int p = 0; p < 19; p++) {
                int j0 = (p < 10) ? (2 * p) : (2 * (p - 10) + 1);
                float lo = (j0 >= 3 && j0 <= 15) ? src[j0 - 3] : 0.0f;
                float hi = (j0 + 1 >= 3 && j0 + 1 <= 15) ? src[j0 - 2] : 0.0f;
                wldsU[dst + p] = pkh(lo, hi);
            }
        }
    }
    __syncthreads();

    // ---- layer 2: 32 -> 16 in two input halves (acc1[16..31] in regs
    // through half 0; written to own row between halves)
    float acc2[16];
    #pragma unroll
    for (int o = 0; o < 16; o++) acc2[o] = 0.0f;

    #pragma unroll 1
    for (int half = 0; half < 2; half++) {
        #pragma unroll 1
        for (int pi = 0; pi < 8; pi++) {
            h2 yp = u2h(hbuf[tid * 9 + ((pi + rot) & 7)]);
            #pragma unroll
            for (int par = 0; par < 2; par++) {
                int i = half * 16 + 2 * pi + par;
                float yv = (par == 0) ? (float)yp.x : (float)yp.y;
                float sx = silu(yv);
                float B0, B1, B2, B3; int m;
                bspline4(yv, B0, B1, B2, B3, m);
                h2 B01 = u2h(pkh(B0, B1));
                h2 B23 = u2h(pkh(B2, B3));
                int poff = (m & 1) ? (10 + ((m - 1) >> 1)) : (m >> 1);
                int base = i * 304 + poff;
                const float* wbrow = wb2 + i;   // wb2[o*32+i]
                #pragma unroll
                for (int o = 0; o < 16; o++) {
                    unsigned int da = wldsU[base + o * 19];
                    unsigned int db = wldsU[base + o * 19 + 1];
                    float a = acc2[o];
                    a = dot2f(B01, u2h(da), a);
                    a = dot2f(B23, u2h(db), a);
                    a = fmaf(sx, wbrow[o * 32], a);
                    acc2[o] = a;
                }
            }
        }
        if (half == 0) {
            #pragma unroll
            for (int op = 0; op < 8; op++)
                hbuf[tid * 9 + ((op + rot) & 7)] =
                    pkh(acc1[16 + 2 * op], acc1[17 + 2 * op]);
        }
    }

    // ---- layer 3: 16 -> 1, fully unrolled, fp32 weights from global
    float acc3 = 0.0f;
    #pragma unroll
    for (int i = 0; i < 16; i++) {
        float xv = acc2[i];
        float sx = silu(xv);
        float B0, B1, B2, B3; int m;
        bspline4(xv, B0, B1, B2, B3, m);
        acc3 = fmaf(sx, wb3[i], acc3);
        const float* w3 = &ws3[i * 13];
        int j0 = m - 3;
        float w0v = (j0 >= 0)              ? w3[j0]     : 0.0f;
        float w1v = (j0 >= -1 && j0 <= 11) ? w3[j0 + 1] : 0.0f;
        float w2v = (j0 >= -2 && j0 <= 10) ? w3[j0 + 2] : 0.0f;
        float w3v = (j0 <= 9)              ? w3[j0 + 3] : 0.0f;
        acc3 = fmaf(B0, w0v, acc3);
        acc3 = fmaf(B1, w1v, acc3);
        acc3 = fmaf(B2, w2v, acc3);
        acc3 = fmaf(B3, w3v, acc3);
    }
    out[row] = acc3;
}

// ---------------------------------------------------------------------------
extern "C" void kernel_launch(void* const* d_in, const int* in_sizes, int n_in,
                              void* d_out, int out_size, void* d_ws, size_t ws_size,
                              hipStream_t stream) {
    const float* x_seq = (const float*)d_in[0];
    const float* wb1   = (const float*)d_in[1];
    const float* ws1   = (const float*)d_in[2];
    const float* wb2   = (const float*)d_in[3];
    const float* ws2   = (const float*)d_in[4];
    const float* wb3   = (const float*)d_in[5];
    const float* ws3   = (const float*)d_in[6];

    float* ws   = (float*)d_ws;
    float* Psub = ws;                   // 128*8*64        =   65536
    float* Vsub = ws + 65536;           // 128*8*64*8      =  524288
    float* Pfin = ws + 589824;          // 128*64          =    8192
    float* Vfin = ws + 598016;          // 128*64*8        =   65536
    float* S0   = ws + 663552;          // 128*64*8        =   65536
    float* out  = (float*)d_out;

    hipLaunchKernelGGL(hippo_chunk_kernel,   dim3(NCH), dim3(128), 0, stream,
                       x_seq, Psub, Vsub, Pfin, Vfin);
    hipLaunchKernelGGL(hippo_compose_kernel, dim3(1),   dim3(512), 0, stream,
                       Pfin, Vfin, S0);
    hipLaunchKernelGGL(kan_kernel, dim3(NROWS / 256), dim3(256), 0, stream,
                       x_seq, Psub, Vsub, S0,
                       wb1, ws1, wb2, ws2, wb3, ws3, out);
}